// Round 10
// baseline (39.223 us; speedup 1.0000x reference)
//
#include <hip/hip_runtime.h>
#include <math.h>

#define TAIL_B 20.0f
#define GI 512              // G * I = 8 * 64
#define BATCH 16384
#define NELEM (BATCH * GI)  // 8,388,608 elements per output tensor
#define ROWS_PB 32          // batch rows per block

typedef float vf4 __attribute__((ext_vector_type(4)));

// LDS tables (float offsets), stride 17 (odd -> conflict-free lane=il gathers):
//   cumw [64][17] @ 0      knot x
//   cumh [64][17] @ 1088   knot y
//   dk   [64][17] @ 2176   derivatives at knots, dk[0]=dk[16]=1
#define LDSF 3264           // 13,056 B -> 8 blocks/CU

__global__ __launch_bounds__(256, 8) void rqs_fused(
    const float* __restrict__ x, const float* __restrict__ W,
    const float* __restrict__ H, const float* __restrict__ D,
    float* __restrict__ out)
{
    __shared__ float s[LDSF];

    int tid   = threadIdx.x;
    int g     = blockIdx.x & 7;
    int chunk = blockIdx.x >> 3;
    int lane  = tid & 63;
    int wsub  = tid >> 6;            // 0..3

    int colbase = g * 64 + lane;
    int rowbase = chunk * ROWS_PB + wsub;

    // ---- prefetch ALL 8 x values (fits VGPR budget; real MLP at 8 waves/SIMD) ----
    float xb[8];
#pragma unroll
    for (int i = 0; i < 8; ++i)
        xb[i] = x[(rowbase + i * 4) * 512 + colbase];

    // ---- cooperative table build: 4 threads per column (quad-lane aligned) ----
    {
        int col = tid >> 2;          // 0..63 (same for the 4 quad lanes)
        int kp  = tid & 3;           // this thread's bins: 4kp..4kp+3
        int gi  = g * 64 + col;
        int qb  = lane & ~3;         // quad base lane

        vf4 wv = *reinterpret_cast<const vf4*>(W + gi * 16 + kp * 4);
        vf4 hv = *reinterpret_cast<const vf4*>(H + gi * 16 + kp * 4);

        float mw = fmaxf(fmaxf(wv.x, wv.y), fmaxf(wv.z, wv.w));
        float mh = fmaxf(fmaxf(hv.x, hv.y), fmaxf(hv.z, hv.w));
        mw = fmaxf(mw, __shfl_xor(mw, 1)); mw = fmaxf(mw, __shfl_xor(mw, 2));
        mh = fmaxf(mh, __shfl_xor(mh, 1)); mh = fmaxf(mh, __shfl_xor(mh, 2));

        float w0 = expf(wv.x - mw), w1 = expf(wv.y - mw),
              w2 = expf(wv.z - mw), w3 = expf(wv.w - mw);
        float h0 = expf(hv.x - mh), h1 = expf(hv.y - mh),
              h2 = expf(hv.z - mh), h3 = expf(hv.w - mh);
        float Tw = w0 + w1 + w2 + w3;
        float Th = h0 + h1 + h2 + h3;

        float tw0 = __shfl(Tw, qb), tw1 = __shfl(Tw, qb + 1),
              tw2 = __shfl(Tw, qb + 2), tw3 = __shfl(Tw, qb + 3);
        float th0 = __shfl(Th, qb), th1 = __shfl(Th, qb + 1),
              th2 = __shfl(Th, qb + 2), th3 = __shfl(Th, qb + 3);
        float scw = (2.0f * TAIL_B) / (tw0 + tw1 + tw2 + tw3);
        float sch = (2.0f * TAIL_B) / (th0 + th1 + th2 + th3);
        float offw = (kp > 0 ? tw0 : 0.f) + (kp > 1 ? tw1 : 0.f) + (kp > 2 ? tw2 : 0.f);
        float offh = (kp > 0 ? th0 : 0.f) + (kp > 1 ? th1 : 0.f) + (kp > 2 ? th2 : 0.f);

        float cwb = -TAIL_B + offw * scw;     // cumw at knot 4kp
        float chb = -TAIL_B + offh * sch;

        float* sc = s + col * 17;
        sc[4 * kp + 1]        = cwb + w0 * scw;
        sc[4 * kp + 2]        = cwb + (w0 + w1) * scw;
        sc[4 * kp + 3]        = cwb + (w0 + w1 + w2) * scw;
        sc[4 * kp + 4]        = cwb + (w0 + w1 + w2 + w3) * scw;
        sc[1088 + 4 * kp + 1] = chb + h0 * sch;
        sc[1088 + 4 * kp + 2] = chb + (h0 + h1) * sch;
        sc[1088 + 4 * kp + 3] = chb + (h0 + h1 + h2) * sch;
        sc[1088 + 4 * kp + 4] = chb + (h0 + h1 + h2 + h3) * sch;

        // derivatives: dk[t] for t = 4kp+1 .. 4kp+4 ; D index t-1, knot16 -> 1
        const float* Dg = D + gi * 15;
#pragma unroll
        for (int j = 0; j < 4; ++j) {
            int t = 4 * kp + 1 + j;
            float dv = 1.0f;
            if (t < 16) {
                float v = Dg[t - 1];
                dv = fmaxf(v, 0.0f) + log1pf(expf(-fabsf(v)));  // stable softplus
            }
            sc[2176 + t] = dv;
        }
        if (kp == 0) {
            sc[0]    = -TAIL_B;
            sc[1088] = -TAIL_B;
            sc[2176] = 1.0f;
        }
    }
    __syncthreads();

    // 15 interior knots -> registers (conflict-free: bank = (17*lane + t) % 32)
    float kr[15];
#pragma unroll
    for (int t = 0; t < 15; ++t) kr[t] = s[lane * 17 + 1 + t];

    const float* sCW = s;
    const float* sCH = s + 1088;
    const float* sDK = s + 2176;

#pragma unroll
    for (int i = 0; i < 8; ++i) {
        float xx = xb[i];
        bool  inside = (xx >= -TAIL_B) && (xx <= TAIL_B);
        float xc = fminf(fmaxf(xx, -TAIL_B), TAIL_B);

        // register-resident bin search: idx = #knots <= xc
        int idx = 0;
#pragma unroll
        for (int t = 0; t < 15; ++t) idx += (xc >= kr[t]) ? 1 : 0;

        int p = lane * 17 + idx;
        float k0  = sCW[p], k1  = sCW[p + 1];
        float ch0 = sCH[p], ch1 = sCH[p + 1];
        float d0  = sDK[p], d1  = sDK[p + 1];

        float invw  = __builtin_amdgcn_rcpf(k1 - k0);
        float hh    = ch1 - ch0;
        float de    = hh * invw;
        float theta = (xc - k0) * invw;
        float omt   = 1.0f - theta;
        float tt    = theta * omt;
        float denom = de + (d0 + d1 - 2.0f * de) * tt;
        float rden  = __builtin_amdgcn_rcpf(denom);
        float numer = hh * (de * theta * theta + d0 * tt);
        float zin   = ch0 + numer * rden;
        float dnum  = de * de * (d1 * theta * theta + 2.0f * de * tt + d0 * omt * omt);
        float ldin  = 0.6931471805599453f * __log2f(dnum * rden * rden);

        float z  = inside ? zin : xx;
        float ld = inside ? ldin : 0.0f;

        int addr = (rowbase + i * 4) * 512 + colbase;
        __builtin_nontemporal_store(z,  out + addr);
        __builtin_nontemporal_store(ld, out + NELEM + addr);
    }
}

extern "C" void kernel_launch(void* const* d_in, const int* in_sizes, int n_in,
                              void* d_out, int out_size, void* d_ws, size_t ws_size,
                              hipStream_t stream)
{
    const float* x = (const float*)d_in[0];
    const float* W = (const float*)d_in[1];
    const float* H = (const float*)d_in[2];
    const float* D = (const float*)d_in[3];
    float* out = (float*)d_out;

    int nblocks = 8 * (BATCH / ROWS_PB);   // 4096 = two exact rounds of 8 blocks/CU
    rqs_fused<<<nblocks, 256, 0, stream>>>(x, W, H, D, out);
}

// Round 11
// 26.284 us; speedup vs baseline: 1.4923x; 1.4923x over previous
//
#include <hip/hip_runtime.h>
#include <math.h>

#define TAIL_B 20.0f
#define BATCH 16384
#define NELEM (BATCH * 512)   // 8,388,608 elements per output tensor
#define ROWS_PB 64            // rows per block -> 256 blocks = 1 per CU
#define LDS_BYTES 104448      // 3 tables * 512 cols * 17 * 4B

typedef float vf4 __attribute__((ext_vector_type(4)));

// Dynamic LDS layout (floats), stride 17 (odd -> conflict-free lane gathers):
//   cumw [512][17] @ 0       knot x
//   cumh [512][17] @ 8704    knot y
//   dk   [512][17] @ 17408   derivatives at knots, dk[0]=dk[16]=1
__global__ __launch_bounds__(1024, 4) void rqs_fused(
    const float* __restrict__ x, const float* __restrict__ W,
    const float* __restrict__ H, const float* __restrict__ D,
    float* __restrict__ out)
{
    extern __shared__ float s[];
    float* sCW = s;
    float* sCH = s + 8704;
    float* sDK = s + 17408;

    const int tid   = threadIdx.x;
    const int col   = tid & 511;          // = gi; contiguous across the block
    const int rsub  = tid >> 9;           // 0..1
    const int rbase = blockIdx.x * ROWS_PB + rsub * 32;

    // ---- batch A prefetch (rows rbase+0..7), issued before prologue ----
    float xbA[8], xbB[8];
#pragma unroll
    for (int i = 0; i < 8; ++i)
        xbA[i] = x[(rbase + i) * 512 + col];

    // ---- prologue: 2 threads per column, runs ONCE per CU ----
    {
        const int c    = tid >> 1;        // 0..511 (column this thread builds)
        const int half = tid & 1;         // bins 8*half .. 8*half+7
        const float* Wg = W + c * 16 + half * 8;
        const float* Hg = H + c * 16 + half * 8;

        vf4 wa = *reinterpret_cast<const vf4*>(Wg);
        vf4 wb = *reinterpret_cast<const vf4*>(Wg + 4);
        vf4 ha = *reinterpret_cast<const vf4*>(Hg);
        vf4 hb = *reinterpret_cast<const vf4*>(Hg + 4);

        float mw = fmaxf(fmaxf(fmaxf(wa.x, wa.y), fmaxf(wa.z, wa.w)),
                         fmaxf(fmaxf(wb.x, wb.y), fmaxf(wb.z, wb.w)));
        float mh = fmaxf(fmaxf(fmaxf(ha.x, ha.y), fmaxf(ha.z, ha.w)),
                         fmaxf(fmaxf(hb.x, hb.y), fmaxf(hb.z, hb.w)));
        mw = fmaxf(mw, __shfl_xor(mw, 1));
        mh = fmaxf(mh, __shfl_xor(mh, 1));

        float ew[8] = {__expf(wa.x - mw), __expf(wa.y - mw), __expf(wa.z - mw), __expf(wa.w - mw),
                       __expf(wb.x - mw), __expf(wb.y - mw), __expf(wb.z - mw), __expf(wb.w - mw)};
        float eh[8] = {__expf(ha.x - mh), __expf(ha.y - mh), __expf(ha.z - mh), __expf(ha.w - mh),
                       __expf(hb.x - mh), __expf(hb.y - mh), __expf(hb.z - mh), __expf(hb.w - mh)};

        float sw = 0.0f, sh = 0.0f;
#pragma unroll
        for (int j = 0; j < 8; ++j) { sw += ew[j]; sh += eh[j]; }
        float swp = __shfl_xor(sw, 1), shp = __shfl_xor(sh, 1);
        float scw = (2.0f * TAIL_B) / (sw + swp);
        float sch = (2.0f * TAIL_B) / (sh + shp);

        float aw = half ? swp : 0.0f;     // exclusive prefix from partner
        float ah = half ? shp : 0.0f;

        const float* Dg = D + c * 15;
        float* cw = sCW + c * 17;
        float* ch = sCH + c * 17;
        float* dk = sDK + c * 17;
        if (!half) { cw[0] = -TAIL_B; ch[0] = -TAIL_B; dk[0] = 1.0f; }

#pragma unroll
        for (int j = 0; j < 8; ++j) {
            aw += ew[j]; ah += eh[j];
            int t = half * 8 + j + 1;     // knot index 1..16
            cw[t] = -TAIL_B + aw * scw;
            ch[t] = -TAIL_B + ah * sch;
            float dv = 1.0f;
            if (t < 16) {
                float v = Dg[t - 1];      // fast stable softplus
                dv = fmaxf(v, 0.0f) + __logf(1.0f + __expf(-fabsf(v)));
            }
            dk[t] = dv;
        }
    }
    __syncthreads();

    // 15 interior knots -> registers (bank = (17*col + t) % 32, conflict-free)
    float kr[15];
#pragma unroll
    for (int t = 0; t < 15; ++t) kr[t] = sCW[col * 17 + 1 + t];

    auto compute8 = [&](const float (&xb)[8], int r0) {
#pragma unroll
        for (int i = 0; i < 8; ++i) {
            float xx = xb[i];
            bool  inside = (xx >= -TAIL_B) && (xx <= TAIL_B);
            float xc = fminf(fmaxf(xx, -TAIL_B), TAIL_B);

            int idx = 0;
#pragma unroll
            for (int t = 0; t < 15; ++t) idx += (xc >= kr[t]) ? 1 : 0;

            int p = col * 17 + idx;
            float k0  = sCW[p], k1  = sCW[p + 1];
            float ch0 = sCH[p], ch1 = sCH[p + 1];
            float d0  = sDK[p], d1  = sDK[p + 1];

            float invw  = __builtin_amdgcn_rcpf(k1 - k0);
            float hh    = ch1 - ch0;
            float de    = hh * invw;
            float theta = (xc - k0) * invw;
            float omt   = 1.0f - theta;
            float tt    = theta * omt;
            float denom = de + (d0 + d1 - 2.0f * de) * tt;
            float rden  = __builtin_amdgcn_rcpf(denom);
            float numer = hh * (de * theta * theta + d0 * tt);
            float zin   = ch0 + numer * rden;
            float dnum  = de * de * (d1 * theta * theta + 2.0f * de * tt + d0 * omt * omt);
            float ldin  = 0.6931471805599453f * __log2f(dnum * rden * rden);

            float z  = inside ? zin : xx;
            float ld = inside ? ldin : 0.0f;

            int addr = (r0 + i) * 512 + col;
            __builtin_nontemporal_store(z,  out + addr);
            __builtin_nontemporal_store(ld, out + NELEM + addr);
        }
    };

    // software pipeline: issue next 8-row batch before computing current
#pragma unroll
    for (int i = 0; i < 8; ++i) xbB[i] = x[(rbase + 8 + i) * 512 + col];
    compute8(xbA, rbase);

#pragma unroll
    for (int i = 0; i < 8; ++i) xbA[i] = x[(rbase + 16 + i) * 512 + col];
    compute8(xbB, rbase + 8);

#pragma unroll
    for (int i = 0; i < 8; ++i) xbB[i] = x[(rbase + 24 + i) * 512 + col];
    compute8(xbA, rbase + 16);

    compute8(xbB, rbase + 24);
}

extern "C" void kernel_launch(void* const* d_in, const int* in_sizes, int n_in,
                              void* d_out, int out_size, void* d_ws, size_t ws_size,
                              hipStream_t stream)
{
    const float* x = (const float*)d_in[0];
    const float* W = (const float*)d_in[1];
    const float* H = (const float*)d_in[2];
    const float* D = (const float*)d_in[3];
    float* out = (float*)d_out;

    hipFuncSetAttribute(reinterpret_cast<const void*>(&rqs_fused),
                        hipFuncAttributeMaxDynamicSharedMemorySize, LDS_BYTES);

    rqs_fused<<<BATCH / ROWS_PB, 1024, LDS_BYTES, stream>>>(x, W, H, D, out);
}